// Round 1
// baseline (586.920 us; speedup 1.0000x reference)
//
#include <hip/hip_runtime.h>
#include <hip/hip_bf16.h>

// Problem: B=8, T=64, N=512, D=64, K=8 heads, d=8.
// One workgroup per (b,n): full fusion QKV -> attention -> FFN in LDS.
// All GEMM operands stored bf16 in LDS, fp32 accumulation (matches harness'
// bf16-scaled threshold; sets up MFMA conversion next round).

#define Bb 8
#define Tt 64
#define Nn 512
#define Dd 64

typedef unsigned short u16;
typedef unsigned int u32;

// LDS strides (shorts). +4 padding makes GEMM read patterns conflict-free.
#define HS 132   // h row stride (128 + 4)
#define WS 132   // staged-W^T row stride
#define QS 68    // q/k/v/attn/a row stride (64 + 4)

// LDS layout (shorts):
//   h   : [64][132] @ 0       (8448)   -- attnout aliases @0 as [64][68]
//   q   : [64][68]  @ 8448    (4352)   -- 'a' (FFN hidden) aliases q
//   k   : [64][68]  @ 12800   (4352)
//   v   : [64][68]  @ 17152   (4352)
//   wT  : [64][132] @ 21504   (8448)   -- current weight, transposed, bf16
// total 29952 shorts = 59904 B  (< 64 KB, 2 blocks/CU)

__device__ inline u16 f2bf(float f) {           // fp32 -> bf16, round-nearest-even
    u32 x = __float_as_uint(f);
    x += 0x7fffu + ((x >> 16) & 1u);
    return (u16)(x >> 16);
}
__device__ inline float bf2f(u16 u) {           // exact
    return __uint_as_float(((u32)u) << 16);
}
__device__ inline void ld8(const u16* __restrict__ p, float* __restrict__ dst) {
    ushort4 a = *(const ushort4*)p;
    ushort4 b = *(const ushort4*)(p + 4);
    dst[0] = bf2f(a.x); dst[1] = bf2f(a.y); dst[2] = bf2f(a.z); dst[3] = bf2f(a.w);
    dst[4] = bf2f(b.x); dst[5] = bf2f(b.y); dst[6] = bf2f(b.z); dst[7] = bf2f(b.w);
}

// 64x64 output GEMM: A[64][KD] (LDS bf16, stride As) @ W^T[64][KD] (LDS bf16,
// stride WS) + bias, optional relu. Writes bf16 LDS (stride Os) or fp32 global
// (row stride N*D). Thread (ty=tid>>4, tx=tid&15) owns rows ty*4..+3, cols
// {tx, tx+16, tx+32, tx+48}.
template<int KD, bool RELU, bool TOGLOBAL>
__device__ void gemm_tile(const u16* __restrict__ A, int As,
                          const u16* __restrict__ WT,
                          const float* __restrict__ bias,
                          u16* __restrict__ O, int Os,
                          float* __restrict__ G, int tid) {
    const int ty = tid >> 4, tx = tid & 15;
    const int r0 = ty * 4;
    float acc[4][4] = {};
    for (int f = 0; f < KD; f += 8) {
        float a8[4][8], w8[4][8];
#pragma unroll
        for (int i = 0; i < 4; ++i) ld8(&A[(r0 + i) * As + f], a8[i]);
#pragma unroll
        for (int m = 0; m < 4; ++m) ld8(&WT[(tx + 16 * m) * WS + f], w8[m]);
#pragma unroll
        for (int i = 0; i < 4; ++i)
#pragma unroll
            for (int m = 0; m < 4; ++m)
#pragma unroll
                for (int l = 0; l < 8; ++l)
                    acc[i][m] = fmaf(a8[i][l], w8[m][l], acc[i][m]);
    }
#pragma unroll
    for (int m = 0; m < 4; ++m) {
        const int c = tx + 16 * m;
        const float bv_ = bias[c];
#pragma unroll
        for (int i = 0; i < 4; ++i) {
            float r = acc[i][m] + bv_;
            if (RELU) r = fmaxf(r, 0.f);
            if (TOGLOBAL) {
                G[(size_t)(r0 + i) * (Nn * Dd) + c] = r;
            } else {
                O[(r0 + i) * Os + c] = f2bf(r);
            }
        }
    }
}

__global__ __launch_bounds__(256)
void ta_fused_kernel(const float* __restrict__ x,  const float* __restrict__ ste,
                     const float* __restrict__ Wq, const float* __restrict__ bq,
                     const float* __restrict__ Wk, const float* __restrict__ bk,
                     const float* __restrict__ Wv, const float* __restrict__ bv,
                     const float* __restrict__ W1, const float* __restrict__ b1,
                     const float* __restrict__ W2, const float* __restrict__ b2,
                     float* __restrict__ out) {
    __shared__ u16 sm[29952];
    u16* h     = sm;             // [64][132]
    u16* qb    = sm + 8448;      // [64][68]
    u16* kb    = sm + 12800;
    u16* vb    = sm + 17152;
    u16* wT    = sm + 21504;     // [64][132]
    u16* attno = sm;             // alias over h: [64][68]
    u16* abuf  = qb;             // alias over q: [64][68]

    const int tid = threadIdx.x;
    const int bid = blockIdx.x;
    const int b = bid >> 9, n = bid & 511;

    const float* xb = x   + (((size_t)b * Tt) * Nn + n) * Dd;
    const float* sb = ste + (((size_t)b * Tt) * Nn + n) * Dd;

    // ---- Phase 0: load h = concat(x, ste) -> bf16 LDS [64][128] ----
#pragma unroll
    for (int l = 0; l < 8; ++l) {
        int idx = l * 256 + tid;            // 0..2047 float4s
        int t = idx >> 5;                   // 32 float4 per row (16 x, 16 ste)
        int p = idx & 31;
        const float* src = (p < 16) ? xb : sb;
        float4 vv = *(const float4*)(src + (size_t)t * (Nn * Dd) + (p & 15) * 4);
        ushort4 st;
        st.x = f2bf(vv.x); st.y = f2bf(vv.y); st.z = f2bf(vv.z); st.w = f2bf(vv.w);
        *(ushort4*)&h[t * HS + p * 4] = st;  // col = p*4 (0..124)
    }

    // weight staging: fp32 W[KD][64] (row-major) -> bf16 wT[c][f]
    auto stageW = [&](const float* __restrict__ W, int KD) {
        int nf4 = KD * 16;
        for (int idx = tid; idx < nf4; idx += 256) {
            int f = idx >> 4, c4 = idx & 15;
            float4 w = *(const float4*)(W + (size_t)idx * 4);
            wT[(c4 * 4 + 0) * WS + f] = f2bf(w.x);
            wT[(c4 * 4 + 1) * WS + f] = f2bf(w.y);
            wT[(c4 * 4 + 2) * WS + f] = f2bf(w.z);
            wT[(c4 * 4 + 3) * WS + f] = f2bf(w.w);
        }
    };

    __syncthreads();

    // ---- Phase 1: q/k/v = relu(h @ W + b) ----
    stageW(Wq, 128); __syncthreads();
    gemm_tile<128, true, false>(h, HS, wT, bq, qb, QS, nullptr, tid); __syncthreads();
    stageW(Wk, 128); __syncthreads();
    gemm_tile<128, true, false>(h, HS, wT, bk, kb, QS, nullptr, tid); __syncthreads();
    stageW(Wv, 128); __syncthreads();
    gemm_tile<128, true, false>(h, HS, wT, bv, vb, QS, nullptr, tid); __syncthreads();

    // ---- Phase 2: causal attention per (head, t); h region is dead ----
    // 512 (head,t) rows over 256 threads -> 2 rows/thread. Single online pass:
    // masked terms contribute exactly 0 (matches exp(-32767 - m) underflow).
#pragma unroll
    for (int pp = 0; pp < 2; ++pp) {
        int pair = tid + pp * 256;
        int head = pair >> 6;               // 0..7
        int t = pair & 63;
        int h8 = head * 8;
        const float scale = 0.35355339059327373f;   // 1/sqrt(8)
        float qq[8];
        ld8(&qb[t * QS + h8], qq);
#pragma unroll
        for (int j = 0; j < 8; ++j) qq[j] *= scale;
        float o[8] = {0.f, 0.f, 0.f, 0.f, 0.f, 0.f, 0.f, 0.f};
        float denom = 0.f;
        for (int s = 0; s < 64; ++s) {      // uniform trip count (no divergence)
            float kk[8];
            ld8(&kb[s * QS + h8], kk);      // broadcast across wave (t varies, head fixed)
            float sc = qq[0] * kk[0];
#pragma unroll
            for (int j = 1; j < 8; ++j) sc = fmaf(qq[j], kk[j], sc);
            float e = __expf(sc);
            if (s > t) e = 0.f;             // causal mask
            denom += e;
            float vv8[8];
            ld8(&vb[s * QS + h8], vv8);
#pragma unroll
            for (int j = 0; j < 8; ++j) o[j] = fmaf(e, vv8[j], o[j]);
        }
        float inv = 1.f / denom;
        ushort4 s0, s1;
        s0.x = f2bf(o[0] * inv); s0.y = f2bf(o[1] * inv);
        s0.z = f2bf(o[2] * inv); s0.w = f2bf(o[3] * inv);
        s1.x = f2bf(o[4] * inv); s1.y = f2bf(o[5] * inv);
        s1.z = f2bf(o[6] * inv); s1.w = f2bf(o[7] * inv);
        *(ushort4*)&attno[t * QS + h8]     = s0;
        *(ushort4*)&attno[t * QS + h8 + 4] = s1;
    }
    __syncthreads();

    // ---- Phase 3: FFN ----
    stageW(W1, 64); __syncthreads();
    gemm_tile<64, true, false>(attno, QS, wT, b1, abuf, QS, nullptr, tid); __syncthreads();
    stageW(W2, 64); __syncthreads();
    float* ob = out + (((size_t)b * Tt) * Nn + n) * Dd;   // row t stride = N*D
    gemm_tile<64, false, true>(abuf, QS, wT, b2, nullptr, 0, ob, tid);
}

extern "C" void kernel_launch(void* const* d_in, const int* in_sizes, int n_in,
                              void* d_out, int out_size, void* d_ws, size_t ws_size,
                              hipStream_t stream) {
    const float* x   = (const float*)d_in[0];
    const float* ste = (const float*)d_in[1];
    const float* Wq  = (const float*)d_in[2];
    const float* bq  = (const float*)d_in[3];
    const float* Wk  = (const float*)d_in[4];
    const float* bk  = (const float*)d_in[5];
    const float* Wv  = (const float*)d_in[6];
    const float* bv  = (const float*)d_in[7];
    const float* W1  = (const float*)d_in[8];
    const float* b1  = (const float*)d_in[9];
    const float* W2  = (const float*)d_in[10];
    const float* b2  = (const float*)d_in[11];
    float* out = (float*)d_out;

    hipLaunchKernelGGL(ta_fused_kernel, dim3(Bb * Nn), dim3(256), 0, stream,
                       x, ste, Wq, bq, Wk, bk, Wv, bv, W1, b1, W2, b2, out);
}

// Round 2
// 281.220 us; speedup vs baseline: 2.0870x; 2.0870x over previous
//
#include <hip/hip_runtime.h>

// B=8, T=64, N=512, D=64, K=8 heads, d=8.
// One workgroup (256 thr = 4 waves) per (b,n). Full fusion in LDS.
// All matmuls on mfma_f32_16x16x32_bf16; softmax in-register with
// shfl butterfly; P transits LDS (C-layout -> A-layout transform).

#define Bb 8
#define Tt 64
#define Nn 512
#define Dd 64

typedef unsigned short u16;
typedef unsigned int u32;
typedef __bf16 bf16x8 __attribute__((ext_vector_type(8)));
typedef float f32x4 __attribute__((ext_vector_type(4)));
typedef short s16x8 __attribute__((ext_vector_type(8)));

// LDS strides in shorts: 136 = 68 dw, 72 = 36 dw; both == 4 (mod 32) dwords
// -> wave64 ds_read_b128 perfectly bank-balanced; rows 16B-aligned.
#define HS 136
#define WS 136
#define QS 72
#define PS 72

__device__ inline u16 f2bf(float f) {             // fp32 -> bf16 RNE
    u32 x = __float_as_uint(f);
    x += 0x7fffu + ((x >> 16) & 1u);
    return (u16)(x >> 16);
}
__device__ inline bf16x8 ldf(const u16* p) { return *(const bf16x8*)p; }
__device__ inline bf16x8 zf8() {
    s16x8 z = {0, 0, 0, 0, 0, 0, 0, 0};
    return __builtin_bit_cast(bf16x8, z);
}

// 64x64 GEMM: A[64][As] bf16 LDS @ WT[64][Ws] bf16 LDS (wT[col][k]) + bias.
// Wave w computes rows 16w..16w+15, all 64 cols (4 col-tiles).
// MODE 0: relu -> bf16 LDS row-major; MODE 1: relu -> bf16 LDS transposed
// (O[col][row], for vT); MODE 2: no relu -> fp32 global (row stride N*D).
template<int KD, int MODE>
__device__ inline void mfma_gemm(const u16* __restrict__ A, int As,
                                 const u16* __restrict__ WT, int Ws,
                                 const float* __restrict__ bias,
                                 u16* __restrict__ O, int Os,
                                 float* __restrict__ G,
                                 int w, int lane, float scale) {
    const int l15 = lane & 15, qd = lane >> 4;
    f32x4 acc[4] = {{0,0,0,0},{0,0,0,0},{0,0,0,0},{0,0,0,0}};
    const u16* arow = &A[(16 * w + l15) * As];
#pragma unroll
    for (int k0 = 0; k0 < KD; k0 += 32) {
        bf16x8 af = ldf(arow + k0 + qd * 8);
#pragma unroll
        for (int ct = 0; ct < 4; ++ct) {
            bf16x8 bfr = ldf(&WT[(16 * ct + l15) * Ws + k0 + qd * 8]);
            acc[ct] = __builtin_amdgcn_mfma_f32_16x16x32_bf16(af, bfr, acc[ct], 0, 0, 0);
        }
    }
#pragma unroll
    for (int ct = 0; ct < 4; ++ct) {
        const int col = 16 * ct + l15;
        const float bv = bias[col];
#pragma unroll
        for (int r = 0; r < 4; ++r) {
            const int row = 16 * w + 4 * qd + r;
            float v = acc[ct][r] + bv;
            if (MODE != 2) v = fmaxf(v, 0.f);
            v *= scale;
            if (MODE == 0)      O[row * Os + col] = f2bf(v);
            else if (MODE == 1) O[col * Os + row] = f2bf(v);
            else                G[(size_t)row * (Nn * Dd) + col] = v;
        }
    }
}

// Stage fp32 W[KD][64] -> bf16 wT[col][k] (stride WS). Thread: c=tid&63
// reads down column c (coalesced across lanes), writes 4 contiguous shorts.
template<int KD>
__device__ inline void stageW(const float* __restrict__ W, u16* __restrict__ wT,
                              int tid) {
    const int c = tid & 63;
    const int g = tid >> 6;
#pragma unroll
    for (int pass = 0; pass < KD / 16; ++pass) {
        const int f0 = (pass * 4 + g) * 4;
        ushort4 st;
        st.x = f2bf(W[(f0 + 0) * 64 + c]);
        st.y = f2bf(W[(f0 + 1) * 64 + c]);
        st.z = f2bf(W[(f0 + 2) * 64 + c]);
        st.w = f2bf(W[(f0 + 3) * 64 + c]);
        *(ushort4*)&wT[c * WS + f0] = st;
    }
}

__global__ __launch_bounds__(256)
void ta_fused_kernel(const float* __restrict__ x,  const float* __restrict__ ste,
                     const float* __restrict__ Wq, const float* __restrict__ bq,
                     const float* __restrict__ Wk, const float* __restrict__ bk,
                     const float* __restrict__ Wv, const float* __restrict__ bv,
                     const float* __restrict__ W1, const float* __restrict__ b1,
                     const float* __restrict__ W2, const float* __restrict__ b2,
                     float* __restrict__ out) {
    // LDS map (shorts):
    //   h   [64][136] @ 0      (dead after QKV)  -- attnout [64][72] @ 0,
    //                                               P 4x[16][72] @ 4608 overlay
    //   wT  [64][136] @ 8704   (free during attention; P spills 512 into it)
    //   qb  [64][72]  @ 17408  (abuf overlays after attention)
    //   kb  [64][72]  @ 22016
    //   vT  [64][72]  @ 26624  (vT[dim][s])
    __shared__ __align__(16) u16 sm[31232];     // 62464 B
    u16* h       = sm;
    u16* wT      = sm + 8704;
    u16* qb      = sm + 17408;
    u16* kb      = sm + 22016;
    u16* vT      = sm + 26624;
    u16* attnout = sm;
    u16* abuf    = qb;

    const int tid  = threadIdx.x;
    const int w    = tid >> 6;
    const int lane = tid & 63;
    const int l15  = lane & 15, qd = lane >> 4;
    const int bid  = blockIdx.x;
    const int b = bid >> 9, n = bid & 511;

    const float* xb = x   + (((size_t)b * Tt) * Nn + n) * Dd;
    const float* sb = ste + (((size_t)b * Tt) * Nn + n) * Dd;

    // ---- Phase 0: h = concat(x, ste) -> bf16 LDS [64][128] ----
#pragma unroll
    for (int l = 0; l < 8; ++l) {
        int idx = l * 256 + tid;            // 2048 float4s
        int t = idx >> 5, p = idx & 31;     // 32 float4 per row
        const float* src = (p < 16) ? xb : sb;
        float4 vv = *(const float4*)(src + (size_t)t * (Nn * Dd) + (p & 15) * 4);
        ushort4 st;
        st.x = f2bf(vv.x); st.y = f2bf(vv.y); st.z = f2bf(vv.z); st.w = f2bf(vv.w);
        *(ushort4*)&h[t * HS + p * 4] = st;
    }
    __syncthreads();

    // ---- Phase 1: QKV ----  (1/sqrt(8) folded into q)
    stageW<128>(Wq, wT, tid); __syncthreads();
    mfma_gemm<128, 0>(h, HS, wT, WS, bq, qb, QS, nullptr, w, lane, 0.35355339059327373f);
    __syncthreads();
    stageW<128>(Wk, wT, tid); __syncthreads();
    mfma_gemm<128, 0>(h, HS, wT, WS, bk, kb, QS, nullptr, w, lane, 1.f);
    __syncthreads();
    stageW<128>(Wv, wT, tid); __syncthreads();
    mfma_gemm<128, 1>(h, HS, wT, WS, bv, vT, QS, nullptr, w, lane, 1.f);
    __syncthreads();

    // ---- Phase 2: attention. Wave w owns t-rows 16w..16w+15, all 8 heads.
    u16* pb = sm + 4608 + 1152 * w;         // wave-private P slice [16][72]
    const bf16x8 z8 = zf8();
#pragma unroll 1
    for (int h8 = 0; h8 < 64; h8 += 8) {
        // scores: S[t][s] = q . k, K padded 8->32 (quads 1-3 zeroed both sides)
        bf16x8 af = (qd == 0) ? ldf(&qb[(16 * w + l15) * QS + h8]) : z8;
        f32x4 sv[4] = {{0,0,0,0},{0,0,0,0},{0,0,0,0},{0,0,0,0}};
#pragma unroll
        for (int ct = 0; ct < 4; ++ct) {
            bf16x8 bfr = (qd == 0) ? ldf(&kb[(16 * ct + l15) * QS + h8]) : z8;
            sv[ct] = __builtin_amdgcn_mfma_f32_16x16x32_bf16(af, bfr, sv[ct], 0, 0, 0);
        }
        // mask + exp (scores are small: no max-subtraction needed; masked
        // entries contribute exactly 0, matching exp(-32767-m) underflow)
        const int tr = 16 * w + 4 * qd;
#pragma unroll
        for (int ct = 0; ct < 4; ++ct) {
            const int sc = 16 * ct + l15;
#pragma unroll
            for (int r = 0; r < 4; ++r)
                sv[ct][r] = (sc <= tr + r) ? __expf(sv[ct][r]) : 0.f;
        }
        // row denominators: in-lane over ct, then butterfly over 16-lane group
        f32x4 dsum = sv[0] + sv[1] + sv[2] + sv[3];
#pragma unroll
        for (int m = 1; m <= 8; m <<= 1) {
#pragma unroll
            for (int r = 0; r < 4; ++r)
                dsum[r] += __shfl_xor(dsum[r], m, 64);
        }
        // P (unnormalized) -> wave-private LDS slice, A-layout-readable
#pragma unroll
        for (int ct = 0; ct < 4; ++ct)
#pragma unroll
            for (int r = 0; r < 4; ++r)
                pb[(4 * qd + r) * PS + 16 * ct + l15] = f2bf(sv[ct][r]);
        // PV: out(16x8) = P(16x64) @ V_h(64x8), N padded 8->16
        f32x4 o = {0, 0, 0, 0};
#pragma unroll
        for (int k0 = 0; k0 < 64; k0 += 32) {
            bf16x8 pa = ldf(&pb[l15 * PS + k0 + qd * 8]);
            int vrow = h8 + (l15 & 7);      // clamped in-bounds for pad lanes
            bf16x8 vfr = (l15 < 8) ? ldf(&vT[vrow * QS + k0 + qd * 8]) : z8;
            o = __builtin_amdgcn_mfma_f32_16x16x32_bf16(pa, vfr, o, 0, 0, 0);
        }
        if (l15 < 8) {
#pragma unroll
            for (int r = 0; r < 4; ++r) {
                float inv = __builtin_amdgcn_rcpf(dsum[r]);
                attnout[(16 * w + 4 * qd + r) * QS + h8 + l15] = f2bf(o[r] * inv);
            }
        }
    }
    __syncthreads();

    // ---- Phase 3: FFN ----
    stageW<64>(W1, wT, tid); __syncthreads();
    mfma_gemm<64, 0>(attnout, QS, wT, WS, b1, abuf, QS, nullptr, w, lane, 1.f);
    __syncthreads();
    stageW<64>(W2, wT, tid); __syncthreads();
    float* ob = out + (((size_t)b * Tt) * Nn + n) * Dd;
    mfma_gemm<64, 2>(abuf, QS, wT, WS, b2, nullptr, 0, ob, w, lane, 1.f);
}

extern "C" void kernel_launch(void* const* d_in, const int* in_sizes, int n_in,
                              void* d_out, int out_size, void* d_ws, size_t ws_size,
                              hipStream_t stream) {
    const float* x   = (const float*)d_in[0];
    const float* ste = (const float*)d_in[1];
    const float* Wq  = (const float*)d_in[2];
    const float* bq  = (const float*)d_in[3];
    const float* Wk  = (const float*)d_in[4];
    const float* bk  = (const float*)d_in[5];
    const float* Wv  = (const float*)d_in[6];
    const float* bv  = (const float*)d_in[7];
    const float* W1  = (const float*)d_in[8];
    const float* b1  = (const float*)d_in[9];
    const float* W2  = (const float*)d_in[10];
    const float* b2  = (const float*)d_in[11];
    float* out = (float*)d_out;

    hipLaunchKernelGGL(ta_fused_kernel, dim3(Bb * Nn), dim3(256), 0, stream,
                       x, ste, Wq, bq, Wk, bk, Wv, bv, W1, b1, W2, b2, out);
}